// Round 17
// baseline (125.722 us; speedup 1.0000x reference)
//
#include <hip/hip_runtime.h>
#include <hip/hip_bf16.h>

typedef __bf16 bf16x8 __attribute__((ext_vector_type(8)));
typedef float  f32x4  __attribute__((ext_vector_type(4)));

// Async global->LDS DMA (no register result: compiler cannot re-roll/sink it).
__device__ __forceinline__ void dma16(const float* g, float* l) {
    typedef const __attribute__((address_space(1))) unsigned int* gp_t;
    typedef __attribute__((address_space(3))) unsigned int*       lp_t;
    __builtin_amdgcn_global_load_lds((gp_t)(const void*)g, (lp_t)(void*)l, 16, 0, 0);
}

// Pre-kernel: transpose B_data [64 k][16384] fp32 -> ws [256 d][64 n][64 k]
// bf16 (2 MB). Runs once per launch (~3us). Fragment-layout: the main kernel
// then loads any B fragment as ONE contiguous 16B global load (L2-resident).
__global__ __launch_bounds__(256) void transpose_B_kernel(
    const float* __restrict__ Bd, unsigned short* __restrict__ ws)
{
    const int d  = blockIdx.x;         // 0..255
    const int t  = threadIdx.x;
    const int n  = t >> 2;             // 0..63
    const int kq = t & 3;              // 0..3 -> k [kq*16, kq*16+16)
    const float* src = Bd + (long)d * 64 + n;          // + k*16384
    unsigned short* dst = ws + (long)d * 4096 + n * 64 + kq * 16;
    union { ushort4 u4[4]; __bf16 e[16]; } pk;
    #pragma unroll
    for (int j = 0; j < 16; ++j)
        pk.e[j] = (__bf16)src[(long)(kq * 16 + j) * 16384];
    #pragma unroll
    for (int i = 0; i < 4; ++i)
        *(ushort4*)(dst + i * 4) = pk.u4[i];
}

// Main kernel = r11 mechanism (56.3us best) with B evicted from LDS to free
// wave slots: ring-only LDS 48KB -> 3 blocks/CU = 12 waves/CU (+50% vs r11's
// 8; the one clean untested lever — r14/r15 falsified traffic & store-path).
// B fragments: 8x 16B global loads from ws per kb (amortized 4 steps),
// issued after the wait at kb-start; compiler inserts exact waits for them.
// NO barriers at all (B-stage gone; ring is wave-private). Counted vmcnt,
// stricter-side table (lower=safe): chunk0 locals0-2 exact 8; later chunks
// locals0-2 24 (r11-proven with the 64-store burst); %4 in {1,2} -> 12
// (exact 16 incl. B); else 8. Swizzles/refill-clamp/store-burst: r11 verbatim.
__global__ __launch_bounds__(256, 3) void sparse_linear_kernel(
    const float* __restrict__ A, const unsigned short* __restrict__ wsB,
    const int* __restrict__ rowi, const int* __restrict__ di,
    float* __restrict__ C)
{
    __shared__ __align__(16) float Aring[4][3][16 * 64];   // 48 KB, ring only

    const int bid = blockIdx.x;
    const int c   = bid & 63;
    const int grp = bid >> 6;          // 0..15 -> rows [grp*512, +512)
    const int t    = threadIdx.x;
    const int lane = t & 63;
    const int w    = t >> 6;           // 0..3

    int koff[4];
    long boff[4];
    #pragma unroll
    for (int s = 0; s < 4; ++s) {
        koff[s] = rowi[s * 64 + c] * 64;
        boff[s] = (long)di[s * 64 + c] * 4096;
    }

    const long wrow0 = (long)grp * 512 + w * 128;   // + q*64 + mt*16

    auto dmaA = [&](int q, int kb, int mt, int slot) {
        float* slotp = &Aring[w][slot][0];
        const long rbase = wrow0 + q * 64 + mt * 16;
        #pragma unroll
        for (int i = 0; i < 4; ++i) {
            const int rr  = i * 4 + (lane >> 4);
            const int kfl = (((lane & 15) * 16) ^ (rr << 4)) >> 2;
            const float* g = A + (rbase + rr) * 4096 + koff[kb] + kfl;
            dma16(g, slotp + i * 256);
        }
    };

    // ---- prologue: fill slots 0..2 = steps 0..2 (q=0, kb=0, mt=0,1,2) ----
    dmaA(0, 0, 0, 0);
    dmaA(0, 0, 1, 1);
    dmaA(0, 0, 2, 2);

    f32x4 acc[4][4];   // [mt][n2] of the current chunk
    #pragma unroll
    for (int m = 0; m < 4; ++m)
        #pragma unroll
        for (int n2 = 0; n2 < 4; ++n2) acc[m][n2] = f32x4{0.f, 0.f, 0.f, 0.f};

    bf16x8 bfr[2][4];  // B fragments of current kb (32 VGPR), held 4 steps

    #pragma unroll 1
    for (int q = 0; q < 2; ++q) {
        #pragma unroll
        for (int local = 0; local < 16; ++local) {
            const int st = q * 16 + local;
            const int kb = local >> 2, mt = local & 3;
            int slot = q + (local % 3);          // (16q+local)%3, q in {0,1}
            if (slot >= 3) slot -= 3;

            // Counted wait (stricter-side exact; see header)
            if (local < 3) {
                if (q == 0) asm volatile("s_waitcnt vmcnt(8)"  ::: "memory");
                else        asm volatile("s_waitcnt vmcnt(24)" ::: "memory");
            } else if ((local & 3) == 1 || (local & 3) == 2) {
                asm volatile("s_waitcnt vmcnt(12)" ::: "memory");
            } else {
                asm volatile("s_waitcnt vmcnt(8)" ::: "memory");
            }
            __builtin_amdgcn_sched_barrier(0);

            // B fragments: 8x 16B loads from ws at each kb start (L2-resident)
            if (mt == 0) {
                const unsigned short* bsrc = wsB + boff[kb];
                #pragma unroll
                for (int kh = 0; kh < 2; ++kh)
                    #pragma unroll
                    for (int n2 = 0; n2 < 4; ++n2) {
                        const int nr = n2 * 16 + (lane & 15);
                        const int k0 = kh * 32 + (lane >> 4) * 8;
                        bfr[kh][n2] = *(const bf16x8*)(bsrc + nr * 64 + k0);
                    }
            }

            // A fragment: swizzled read from ring slot; convert fp32->bf16
            const char* ab = (const char*)&Aring[w][slot][0];
            const int r   = lane & 15;
            const int q32 = (lane >> 4) * 32;
            f32x4 a0 = *(const f32x4*)(ab + r * 256 + ((q32)            ^ (r << 4)));
            f32x4 a1 = *(const f32x4*)(ab + r * 256 + ((q32 + 16)       ^ (r << 4)));
            f32x4 a2 = *(const f32x4*)(ab + r * 256 + ((128 + q32)      ^ (r << 4)));
            f32x4 a3 = *(const f32x4*)(ab + r * 256 + ((128 + q32 + 16) ^ (r << 4)));
            union { bf16x8 v; __bf16 e[8]; } af0, af1;
            #pragma unroll
            for (int i = 0; i < 4; ++i) {
                af0.e[i]     = (__bf16)a0[i];
                af0.e[i + 4] = (__bf16)a1[i];
                af1.e[i]     = (__bf16)a2[i];
                af1.e[i + 4] = (__bf16)a3[i];
            }

            // Refill this slot for step st+3 (every step; tail clamped)
            {
                int l2 = local + 3, q2 = q;
                if (l2 >= 16) { l2 -= 16; ++q2; }
                if (q2 > 1) { q2 = 1; l2 = 15; }   // harmless redundant DMA at tail
                dmaA(q2, l2 >> 2, l2 & 3, slot);
            }

            // 8 MFMAs for this (kb, mt)
            __builtin_amdgcn_s_setprio(1);
            #pragma unroll
            for (int kh = 0; kh < 2; ++kh) {
                const bf16x8 afv = kh ? af1.v : af0.v;
                #pragma unroll
                for (int n2 = 0; n2 < 4; ++n2)
                    acc[mt][n2] = __builtin_amdgcn_mfma_f32_16x16x32_bf16(afv, bfr[kh][n2], acc[mt][n2], 0, 0, 0);
            }
            __builtin_amdgcn_s_setprio(0);

            // Chunk boundary: store this chunk's C (NT burst, r11-proven)
            if (local == 15) {
                __builtin_amdgcn_sched_barrier(0);
                #pragma unroll
                for (int mts = 0; mts < 4; ++mts) {
                    const long crow0 = wrow0 + q * 64 + mts * 16 + (lane >> 4) * 4;
                    const long col0  = (long)c * 64 + (lane & 15);
                    #pragma unroll
                    for (int n2 = 0; n2 < 4; ++n2) {
                        #pragma unroll
                        for (int v = 0; v < 4; ++v)
                            __builtin_nontemporal_store(acc[mts][n2][v],
                                &C[(crow0 + v) * 4096 + col0 + n2 * 16]);
                        acc[mts][n2] = f32x4{0.f, 0.f, 0.f, 0.f};
                    }
                }
                __builtin_amdgcn_sched_barrier(0);
            }
        }
    }

    asm volatile("s_waitcnt vmcnt(0)" ::: "memory");   // drain tail DMAs/stores
}

extern "C" void kernel_launch(void* const* d_in, const int* in_sizes, int n_in,
                              void* d_out, int out_size, void* d_ws, size_t ws_size,
                              hipStream_t stream) {
    const float* A    = (const float*)d_in[0];
    const float* Bd   = (const float*)d_in[1];
    const int*   rowi = (const int*)d_in[2];
    const int*   di   = (const int*)d_in[3];
    float*       C    = (float*)d_out;
    unsigned short* ws = (unsigned short*)d_ws;   // 2 MB bf16 transposed B

    hipLaunchKernelGGL(transpose_B_kernel, dim3(256), dim3(256), 0, stream, Bd, ws);

    dim3 grid(16 * 64);   // 16 row-groups x 64 columns = 1024 blocks (3/CU resident)
    dim3 block(256);
    hipLaunchKernelGGL(sparse_linear_kernel, grid, block, 0, stream,
                       A, ws, rowi, di, C);
}

// Round 18
// 56.305 us; speedup vs baseline: 2.2329x; 2.2329x over previous
//
#include <hip/hip_runtime.h>
#include <hip/hip_bf16.h>

typedef __bf16 bf16x8 __attribute__((ext_vector_type(8)));
typedef float  f32x4  __attribute__((ext_vector_type(4)));

// Async global->LDS DMA (no register result: compiler cannot re-roll/sink it).
__device__ __forceinline__ void dma16(const float* g, float* l) {
    typedef const __attribute__((address_space(1))) unsigned int* gp_t;
    typedef __attribute__((address_space(3))) unsigned int*       lp_t;
    __builtin_amdgcn_global_load_lds((gp_t)(const void*)g, (lp_t)(void*)l, 16, 0, 0);
}

// EXACT r11 (best: 56.3us) with ONE change: the chunk-boundary 64-store burst
// (a 4x-per-wave partial pipeline flush: vmcnt(24) against 12 loads + 64
// stores retired ~52 ops at once) is replaced by SPREAD stores — 16 NT dwords
// (one m-tile) at each of locals 0-3 of the NEXT chunk, store-old -> zero ->
// accumulate (r14-validated pattern). Exact in-order vmcnt table for gap=3,
// 4 loads/step, 16 stores at locals 0-3 (q>=1): target = refill issued at
// st-3; younger = 8 loads + 16 per store-step in {st-2, st-1}:
//   local 0 -> 8, 1 -> 24, 2..4 -> 40, 5 -> 24, >=6 -> 8  (all <= 63).
// Everything else byte-identical to r11: persistent 512 blocks (64c x 8 grp)
// = 2/CU, per-wave private 3-slot DMA ring, pre-swizzled source (linear dest,
// XOR rr<<4 on read, 0 conflicts), zero main-loop barriers, counted vmcnt
// never 0 mid-loop, B staged once, bfr register-held per kb, NT stores.
__global__ __launch_bounds__(256, 2) void sparse_linear_kernel(
    const float* __restrict__ A, const float* __restrict__ Bd,
    const int* __restrict__ rowi, const int* __restrict__ di,
    float* __restrict__ C)
{
    __shared__ __align__(16) float Aring[4][3][16 * 64];       // 48 KB
    __shared__ __align__(16) unsigned short Bt[4 * 64 * 64];   // 32 KB
    char* BtB = (char*)Bt;

    const int bid = blockIdx.x;
    const int c   = bid & 63;          // sharers c,c+16j differ by 16 in bid -> same XCD (L2 A-reuse)
    const int grp = bid >> 6;          // 0..7 -> rows [grp*1024, +1024)
    const int t    = threadIdx.x;
    const int lane = t & 63;
    const int w    = t >> 6;           // 0..3

    int rs[4], ds[4];
    #pragma unroll
    for (int s = 0; s < 4; ++s) {
        rs[s] = rowi[s * 64 + c];
        ds[s] = di[s * 64 + c];
    }
    int koff[4];
    #pragma unroll
    for (int s = 0; s < 4; ++s) koff[s] = rs[s] * 64;

    const long wrow0 = (long)grp * 1024 + w * 64;   // + q*256 + mt*16

    auto dmaA = [&](int q, int kb, int mt, int slot) {
        float* slotp = &Aring[w][slot][0];
        #pragma unroll
        for (int i = 0; i < 4; ++i) {
            const int rr  = i * 4 + (lane >> 4);
            const int kfl = (((lane & 15) * 16) ^ (rr << 4)) >> 2;
            const float* g = A + (wrow0 + q * 256 + mt * 16 + rr) * 4096 + koff[kb] + kfl;
            dma16(g, slotp + i * 256);
        }
    };

    // ---- prologue: fill slots 0..2 = steps 0..2 (q=0, kb=0, mt=0,1,2) ----
    dmaA(0, 0, 0, 0);
    dmaA(0, 0, 1, 1);
    dmaA(0, 0, 2, 2);

    // ---- stage B once: wave sb stages block sb; lane n owns column n ----
    {
        const int n  = t & 63;
        const int sb = t >> 6;
        const float* Bg = Bd + (long)ds[sb] * 64 + n;   // row stride = BN*TB = 16384
        char* dst = BtB + sb * 8192 + n * 128;
        const int sw = (n & 7) << 4;
        #pragma unroll
        for (int k4 = 0; k4 < 16; ++k4) {
            union { ushort4 u4; __bf16 e[4]; } pk;
            pk.e[0] = (__bf16)Bg[(long)(4 * k4 + 0) * 16384];
            pk.e[1] = (__bf16)Bg[(long)(4 * k4 + 1) * 16384];
            pk.e[2] = (__bf16)Bg[(long)(4 * k4 + 2) * 16384];
            pk.e[3] = (__bf16)Bg[(long)(4 * k4 + 3) * 16384];
            *(ushort4*)(dst + ((8 * k4) ^ sw)) = pk.u4;
        }
    }
    __syncthreads();   // the only barrier (drains prologue DMAs + B writes)

    f32x4 acc[4][4];   // [mt][n2] for the current chunk
    #pragma unroll
    for (int m = 0; m < 4; ++m)
        #pragma unroll
        for (int n2 = 0; n2 < 4; ++n2) acc[m][n2] = f32x4{0.f, 0.f, 0.f, 0.f};

    bf16x8 bfr[2][4];  // B fragments of current kb, register-held 4 steps

    #pragma unroll 1
    for (int q = 0; q < 4; ++q) {
        const int qm3 = q % 3;   // slot base: (16q+local)%3 = (q+local)%3

        #pragma unroll
        for (int local = 0; local < 16; ++local) {
            const int kb = local >> 2, mt = local & 3;
            int slot = qm3 + (local % 3);
            if (slot >= 3) slot -= 3;

            // Exact in-order counted wait (see header table).
            if (local == 1)                    asm volatile("s_waitcnt vmcnt(24)" ::: "memory");
            else if (local >= 2 && local <= 4) asm volatile("s_waitcnt vmcnt(40)" ::: "memory");
            else if (local == 5)               asm volatile("s_waitcnt vmcnt(24)" ::: "memory");
            else                               asm volatile("s_waitcnt vmcnt(8)"  ::: "memory");
            __builtin_amdgcn_sched_barrier(0);

            // Spread prev-chunk C stores: 16 NT dwords (m-tile = local) at
            // locals 0-3 of q>=1; store-old -> zero (MFMA below re-accumulates).
            if (q >= 1 && local < 4) {
                const int mts = local;
                const long crow0 = wrow0 + (q - 1) * 256 + mts * 16 + (lane >> 4) * 4;
                const long col0  = (long)c * 64 + (lane & 15);
                #pragma unroll
                for (int n2 = 0; n2 < 4; ++n2) {
                    #pragma unroll
                    for (int v = 0; v < 4; ++v)
                        __builtin_nontemporal_store(acc[mts][n2][v],
                            &C[(crow0 + v) * 4096 + col0 + n2 * 16]);
                    acc[mts][n2] = f32x4{0.f, 0.f, 0.f, 0.f};
                }
            }

            // B fragments: refresh once per kb (register-held across 4 steps)
            if (mt == 0) {
                const char* bbase = BtB + kb * 8192;
                #pragma unroll
                for (int kh = 0; kh < 2; ++kh)
                    #pragma unroll
                    for (int n2 = 0; n2 < 4; ++n2) {
                        const int nr = n2 * 16 + (lane & 15);
                        const int kbyte = kh * 64 + (lane >> 4) * 16;
                        bfr[kh][n2] = *(const bf16x8*)(bbase + nr * 128 + (kbyte ^ ((nr & 7) << 4)));
                    }
            }

            // A fragment: swizzled read from ring slot; convert fp32->bf16
            const char* ab = (const char*)&Aring[w][slot][0];
            const int r   = lane & 15;
            const int q32 = (lane >> 4) * 32;
            f32x4 a0 = *(const f32x4*)(ab + r * 256 + ((q32)            ^ (r << 4)));
            f32x4 a1 = *(const f32x4*)(ab + r * 256 + ((q32 + 16)       ^ (r << 4)));
            f32x4 a2 = *(const f32x4*)(ab + r * 256 + ((128 + q32)      ^ (r << 4)));
            f32x4 a3 = *(const f32x4*)(ab + r * 256 + ((128 + q32 + 16) ^ (r << 4)));
            union { bf16x8 v; __bf16 e[8]; } af0, af1;
            #pragma unroll
            for (int i = 0; i < 4; ++i) {
                af0.e[i]     = (__bf16)a0[i];
                af0.e[i + 4] = (__bf16)a1[i];
                af1.e[i]     = (__bf16)a2[i];
                af1.e[i + 4] = (__bf16)a3[i];
            }

            // 8 MFMAs for this (kb, mt)
            __builtin_amdgcn_s_setprio(1);
            #pragma unroll
            for (int kh = 0; kh < 2; ++kh) {
                const bf16x8 afv = kh ? af1.v : af0.v;
                #pragma unroll
                for (int n2 = 0; n2 < 4; ++n2)
                    acc[mt][n2] = __builtin_amdgcn_mfma_f32_16x16x32_bf16(afv, bfr[kh][n2], acc[mt][n2], 0, 0, 0);
            }
            __builtin_amdgcn_s_setprio(0);

            // Refill this slot for step+3 (every step; tail clamped).
            {
                int l2 = local + 3, q2 = q;
                if (l2 >= 16) { l2 -= 16; ++q2; }
                if (q2 > 3) q2 = 3;                 // harmless redundant DMA at tail
                dmaA(q2, l2 >> 2, l2 & 3, slot);
            }
        }
    }

    // ---- epilogue: drain, then store the last chunk (q=3) ----
    asm volatile("s_waitcnt vmcnt(0)" ::: "memory");
    #pragma unroll
    for (int mts = 0; mts < 4; ++mts) {
        const long crow0 = wrow0 + 3 * 256 + mts * 16 + (lane >> 4) * 4;
        const long col0  = (long)c * 64 + (lane & 15);
        #pragma unroll
        for (int n2 = 0; n2 < 4; ++n2)
            #pragma unroll
            for (int v = 0; v < 4; ++v)
                __builtin_nontemporal_store(acc[mts][n2][v],
                    &C[(crow0 + v) * 4096 + col0 + n2 * 16]);
    }
}

extern "C" void kernel_launch(void* const* d_in, const int* in_sizes, int n_in,
                              void* d_out, int out_size, void* d_ws, size_t ws_size,
                              hipStream_t stream) {
    const float* A    = (const float*)d_in[0];
    const float* Bd   = (const float*)d_in[1];
    const int*   rowi = (const int*)d_in[2];
    const int*   di   = (const int*)d_in[3];
    float*       C    = (float*)d_out;

    dim3 grid(8 * 64);    // 8 row-groups x 64 columns = 512 blocks = 2/CU, 1 generation
    dim3 block(256);
    hipLaunchKernelGGL(sparse_linear_kernel, grid, block, 0, stream,
                       A, Bd, rowi, di, C);
}